// Round 1
// baseline (1071.710 us; speedup 1.0000x reference)
//
#include <hip/hip_runtime.h>

#define IRREPS 240
#define CHUNKS 60  // IRREPS/4 float4 chunks per edge

__global__ void scatter_add_kernel(const float* __restrict__ msgs,
                                   const int* __restrict__ eidx,
                                   const float* __restrict__ cutoff,
                                   float* __restrict__ agg,
                                   int n_edges) {
    long long tid = (long long)blockIdx.x * blockDim.x + threadIdx.x;
    long long total = (long long)n_edges * CHUNKS;
    if (tid >= total) return;
    int e = (int)(tid / CHUNKS);
    int q = (int)(tid % CHUNKS);
    float w = cutoff[e];
    int tgt = eidx[2 * e + 1];
    const float4 m = *reinterpret_cast<const float4*>(msgs + (long long)e * IRREPS + q * 4);
    float* dst = agg + (long long)tgt * IRREPS + q * 4;
    atomicAdd(dst + 0, m.x * w);
    atomicAdd(dst + 1, m.y * w);
    atomicAdd(dst + 2, m.z * w);
    atomicAdd(dst + 3, m.w * w);
}

__global__ void equivariant_linear_kernel(const float* __restrict__ agg,
                                          const float* __restrict__ W0,
                                          const float* __restrict__ W1,
                                          const float* __restrict__ W2,
                                          float* __restrict__ out,
                                          int n_nodes) {
    __shared__ float s[IRREPS];
    int n = blockIdx.x;
    int t = threadIdx.x;
    if (t < IRREPS) s[t] = agg[(long long)n * IRREPS + t];
    __syncthreads();
    if (t >= IRREPS) return;

    float acc = 0.f;
    float res;
    if (t < 64) {
        // deg-1 block: 64x64, out[n, o] = sum_i W0[o,i] * s[i]
        int o = t;
        #pragma unroll 8
        for (int i = 0; i < 64; ++i) acc += W0[o * 64 + i] * s[i];
        res = acc * 0.125f;               // 1/sqrt(64)
    } else if (t < 160) {
        // deg-3 block: 32 channels x 3 components
        int rel = t - 64;
        int o = rel / 3, d = rel % 3;
        #pragma unroll 8
        for (int i = 0; i < 32; ++i) acc += W1[o * 32 + i] * s[64 + i * 3 + d];
        res = acc * 0.17677669529663687f; // 1/sqrt(32)
    } else {
        // deg-5 block: 16 channels x 5 components
        int rel = t - 160;
        int o = rel / 5, d = rel % 5;
        #pragma unroll
        for (int i = 0; i < 16; ++i) acc += W2[o * 16 + i] * s[160 + i * 5 + d];
        res = acc * 0.25f;                // 1/sqrt(16)
    }
    out[(long long)n * IRREPS + t] = res;
}

extern "C" void kernel_launch(void* const* d_in, const int* in_sizes, int n_in,
                              void* d_out, int out_size, void* d_ws, size_t ws_size,
                              hipStream_t stream) {
    const float* msgs   = (const float*)d_in[0];
    const int*   eidx   = (const int*)d_in[1];
    const float* cutoff = (const float*)d_in[2];
    const float* W0     = (const float*)d_in[3];
    const float* W1     = (const float*)d_in[4];
    const float* W2     = (const float*)d_in[5];

    int n_edges = in_sizes[0] / IRREPS;
    int n_nodes = out_size / IRREPS;

    float* agg = (float*)d_ws;
    hipMemsetAsync(agg, 0, (size_t)n_nodes * IRREPS * sizeof(float), stream);

    {
        long long total = (long long)n_edges * CHUNKS;
        int block = 256;
        int grid = (int)((total + block - 1) / block);
        scatter_add_kernel<<<grid, block, 0, stream>>>(msgs, eidx, cutoff, agg, n_edges);
    }
    {
        equivariant_linear_kernel<<<n_nodes, 256, 0, stream>>>(
            agg, W0, W1, W2, (float*)d_out, n_nodes);
    }
}

// Round 2
// 216.149 us; speedup vs baseline: 4.9582x; 4.9582x over previous
//
#include <hip/hip_runtime.h>

#define IRREPS 240

// ---------- CSR build ----------
__global__ void histogram_kernel(const int* __restrict__ eidx, int* __restrict__ counts,
                                 int n_edges) {
    int e = blockIdx.x * blockDim.x + threadIdx.x;
    if (e >= n_edges) return;
    atomicAdd(&counts[eidx[2 * e + 1]], 1);
}

// single-block exclusive scan over counts -> offsets (and cursor copy)
__global__ void scan_kernel(const int* __restrict__ counts, int* __restrict__ offsets,
                            int* __restrict__ cursor, int n) {
    __shared__ int part[1024];
    int t = threadIdx.x;
    int per = (n + 1023) / 1024;
    int start = t * per;
    int end = min(start + per, n);
    int sum = 0;
    for (int i = start; i < end; ++i) sum += counts[i];
    part[t] = sum;
    __syncthreads();
    // Hillis-Steele inclusive scan
    for (int off = 1; off < 1024; off <<= 1) {
        int v = (t >= off) ? part[t - off] : 0;
        __syncthreads();
        part[t] += v;
        __syncthreads();
    }
    int run = (t == 0) ? 0 : part[t - 1];
    for (int i = start; i < end; ++i) {
        offsets[i] = run;
        cursor[i] = run;
        run += counts[i];
    }
}

__global__ void fill_kernel(const int* __restrict__ eidx, int* __restrict__ cursor,
                            int* __restrict__ edge_ids, int n_edges) {
    int e = blockIdx.x * blockDim.x + threadIdx.x;
    if (e >= n_edges) return;
    int tgt = eidx[2 * e + 1];
    int pos = atomicAdd(&cursor[tgt], 1);
    edge_ids[pos] = e;
}

// ---------- fused gather + equivariant linear ----------
__global__ void gather_linear_kernel(const float* __restrict__ msgs,
                                     const float* __restrict__ cutoff,
                                     const int* __restrict__ edge_ids,
                                     const int* __restrict__ offsets,
                                     const int* __restrict__ counts,
                                     const float* __restrict__ W0,
                                     const float* __restrict__ W1,
                                     const float* __restrict__ W2,
                                     float* __restrict__ out) {
    __shared__ float s[IRREPS];
    int n = blockIdx.x;
    int t = threadIdx.x;

    int beg = offsets[n];
    int cnt = counts[n];

    if (t < IRREPS) {
        float acc = 0.f;
        for (int j = beg; j < beg + cnt; ++j) {
            int e = edge_ids[j];
            float w = cutoff[e];
            acc += msgs[(long long)e * IRREPS + t] * w;
        }
        s[t] = acc;
    }
    __syncthreads();
    if (t >= IRREPS) return;

    float acc = 0.f;
    float res;
    if (t < 64) {
        int o = t;
        #pragma unroll 8
        for (int i = 0; i < 64; ++i) acc += W0[o * 64 + i] * s[i];
        res = acc * 0.125f;               // 1/sqrt(64)
    } else if (t < 160) {
        int rel = t - 64;
        int o = rel / 3, d = rel % 3;
        #pragma unroll 8
        for (int i = 0; i < 32; ++i) acc += W1[o * 32 + i] * s[64 + i * 3 + d];
        res = acc * 0.17677669529663687f; // 1/sqrt(32)
    } else {
        int rel = t - 160;
        int o = rel / 5, d = rel % 5;
        #pragma unroll
        for (int i = 0; i < 16; ++i) acc += W2[o * 16 + i] * s[160 + i * 5 + d];
        res = acc * 0.25f;                // 1/sqrt(16)
    }
    out[(long long)n * IRREPS + t] = res;
}

extern "C" void kernel_launch(void* const* d_in, const int* in_sizes, int n_in,
                              void* d_out, int out_size, void* d_ws, size_t ws_size,
                              hipStream_t stream) {
    const float* msgs   = (const float*)d_in[0];
    const int*   eidx   = (const int*)d_in[1];
    const float* cutoff = (const float*)d_in[2];
    const float* W0     = (const float*)d_in[3];
    const float* W1     = (const float*)d_in[4];
    const float* W2     = (const float*)d_in[5];

    int n_edges = in_sizes[0] / IRREPS;
    int n_nodes = out_size / IRREPS;

    // workspace layout (ints)
    int* counts   = (int*)d_ws;
    int* offsets  = counts + n_nodes;
    int* cursor   = offsets + n_nodes;
    int* edge_ids = cursor + n_nodes;

    hipMemsetAsync(counts, 0, (size_t)n_nodes * sizeof(int), stream);

    int block = 256;
    int egrid = (n_edges + block - 1) / block;
    histogram_kernel<<<egrid, block, 0, stream>>>(eidx, counts, n_edges);
    scan_kernel<<<1, 1024, 0, stream>>>(counts, offsets, cursor, n_nodes);
    fill_kernel<<<egrid, block, 0, stream>>>(eidx, cursor, edge_ids, n_edges);
    gather_linear_kernel<<<n_nodes, 256, 0, stream>>>(
        msgs, cutoff, edge_ids, offsets, counts, W0, W1, W2, (float*)d_out);
}

// Round 3
// 178.527 us; speedup vs baseline: 6.0031x; 1.2107x over previous
//
#include <hip/hip_runtime.h>

#define IRREPS 240
#define BATCH 64

// ---------- CSR build ----------
__global__ void histogram_kernel(const int* __restrict__ eidx, int* __restrict__ counts,
                                 int n_edges) {
    int e = blockIdx.x * blockDim.x + threadIdx.x;
    if (e >= n_edges) return;
    atomicAdd(&counts[eidx[2 * e + 1]], 1);
}

// single-block exclusive scan over counts -> offsets (and cursor copy)
__global__ void scan_kernel(const int* __restrict__ counts, int* __restrict__ offsets,
                            int* __restrict__ cursor, int n) {
    __shared__ int part[1024];
    int t = threadIdx.x;
    int per = (n + 1023) / 1024;
    int start = t * per;
    int end = min(start + per, n);
    int sum = 0;
    for (int i = start; i < end; ++i) sum += counts[i];
    part[t] = sum;
    __syncthreads();
    for (int off = 1; off < 1024; off <<= 1) {
        int v = (t >= off) ? part[t - off] : 0;
        __syncthreads();
        part[t] += v;
        __syncthreads();
    }
    int run = (t == 0) ? 0 : part[t - 1];
    for (int i = start; i < end; ++i) {
        offsets[i] = run;
        cursor[i] = run;
        run += counts[i];
    }
}

__global__ void fill_kernel(const int* __restrict__ eidx, int* __restrict__ cursor,
                            int* __restrict__ edge_ids, int n_edges) {
    int e = blockIdx.x * blockDim.x + threadIdx.x;
    if (e >= n_edges) return;
    int tgt = eidx[2 * e + 1];
    int pos = atomicAdd(&cursor[tgt], 1);
    edge_ids[pos] = e;
}

// ---------- fused gather + equivariant linear ----------
// Block = 256 threads = 4 waves. Wave es owns edge-slots es, es+4, ...
// Lanes 0..59 of each wave hold a float4 slice of the 240-float row.
__global__ void gather_linear_kernel(const float* __restrict__ msgs,
                                     const float* __restrict__ cutoff,
                                     const int* __restrict__ edge_ids,
                                     const int* __restrict__ offsets,
                                     const int* __restrict__ counts,
                                     const float* __restrict__ W0,
                                     const float* __restrict__ W1,
                                     const float* __restrict__ W2,
                                     float* __restrict__ out) {
    __shared__ int   s_eid[BATCH];
    __shared__ float s_w[BATCH];
    __shared__ float s_part[4][IRREPS];
    __shared__ float s[IRREPS];

    int n = blockIdx.x;
    int t = threadIdx.x;
    int es = t >> 6;   // wave id 0..3 = edge slot
    int lane = t & 63;

    int beg = offsets[n];
    int cnt = counts[n];

    float4 acc = make_float4(0.f, 0.f, 0.f, 0.f);

    for (int base = 0; base < cnt; base += BATCH) {
        int bn = min(BATCH, cnt - base);
        if (t < bn) {
            int e = edge_ids[beg + base + t];
            s_eid[t] = e;
            s_w[t] = cutoff[e];
        }
        __syncthreads();
        if (lane < 60) {
            #pragma unroll 4
            for (int i = es; i < bn; i += 4) {
                int e = s_eid[i];
                float w = s_w[i];
                const float4 m = *reinterpret_cast<const float4*>(
                    msgs + (long long)e * IRREPS + lane * 4);
                acc.x += m.x * w;
                acc.y += m.y * w;
                acc.z += m.z * w;
                acc.w += m.w * w;
            }
        }
        __syncthreads();
    }

    if (lane < 60) {
        *reinterpret_cast<float4*>(&s_part[es][lane * 4]) = acc;
    }
    __syncthreads();
    if (t < IRREPS) {
        s[t] = s_part[0][t] + s_part[1][t] + s_part[2][t] + s_part[3][t];
    }
    __syncthreads();
    if (t >= IRREPS) return;

    float a = 0.f;
    float res;
    if (t < 64) {
        int o = t;
        #pragma unroll 8
        for (int i = 0; i < 64; ++i) a += W0[o * 64 + i] * s[i];
        res = a * 0.125f;               // 1/sqrt(64)
    } else if (t < 160) {
        int rel = t - 64;
        int o = rel / 3, d = rel % 3;
        #pragma unroll 8
        for (int i = 0; i < 32; ++i) a += W1[o * 32 + i] * s[64 + i * 3 + d];
        res = a * 0.17677669529663687f; // 1/sqrt(32)
    } else {
        int rel = t - 160;
        int o = rel / 5, d = rel % 5;
        #pragma unroll
        for (int i = 0; i < 16; ++i) a += W2[o * 16 + i] * s[160 + i * 5 + d];
        res = a * 0.25f;                // 1/sqrt(16)
    }
    out[(long long)n * IRREPS + t] = res;
}

extern "C" void kernel_launch(void* const* d_in, const int* in_sizes, int n_in,
                              void* d_out, int out_size, void* d_ws, size_t ws_size,
                              hipStream_t stream) {
    const float* msgs   = (const float*)d_in[0];
    const int*   eidx   = (const int*)d_in[1];
    const float* cutoff = (const float*)d_in[2];
    const float* W0     = (const float*)d_in[3];
    const float* W1     = (const float*)d_in[4];
    const float* W2     = (const float*)d_in[5];

    int n_edges = in_sizes[0] / IRREPS;
    int n_nodes = out_size / IRREPS;

    int* counts   = (int*)d_ws;
    int* offsets  = counts + n_nodes;
    int* cursor   = offsets + n_nodes;
    int* edge_ids = cursor + n_nodes;

    hipMemsetAsync(counts, 0, (size_t)n_nodes * sizeof(int), stream);

    int block = 256;
    int egrid = (n_edges + block - 1) / block;
    histogram_kernel<<<egrid, block, 0, stream>>>(eidx, counts, n_edges);
    scan_kernel<<<1, 1024, 0, stream>>>(counts, offsets, cursor, n_nodes);
    fill_kernel<<<egrid, block, 0, stream>>>(eidx, cursor, edge_ids, n_edges);
    gather_linear_kernel<<<n_nodes, 256, 0, stream>>>(
        msgs, cutoff, edge_ids, offsets, counts, W0, W1, W2, (float*)d_out);
}